// Round 6
// baseline (428.591 us; speedup 1.0000x reference)
//
#include <hip/hip_runtime.h>
#include <math.h>

// Problem dims (fixed by reference)
#define T_DIM 512
#define H_DIM 2048
#define I_DIM 1024
#define E_DIM 16
#define NP    2048          // T*K pairs
#define PM    256           // pairs per chunk: >= max expert count -> 1 chunk/expert, weights read ONCE
#define MAXCH 24            // worst-case chunks: NP/PM + E_DIM
#define LIST_OFF 256        // int offset of sorted pair list in ws
#define HWS_OFF  8192       // float offset of h buffer in ws
#define BK2   64            // K staged per step (half a scale block)
#define LDB   72            // padded bf16 leading dim (144 B stride -> benign aliasing)

typedef float  float4v __attribute__((ext_vector_type(4)));
typedef unsigned int uint4v __attribute__((ext_vector_type(4)));
typedef short  short8v __attribute__((ext_vector_type(8)));

// f32 -> bf16 round-to-nearest-even (bit pattern) — epilogue only
__device__ __forceinline__ unsigned int bfr(float f) {
    unsigned int u = __builtin_bit_cast(unsigned int, f);
    return (u + 0x7fffu + ((u >> 16) & 1u)) >> 16;
}
// HW packed f32x2 -> bf16x2, RNE (gfx950 v_cvt_pk_bf16_f32). lo=a, hi=b.
__device__ __forceinline__ unsigned int cvt2(float a, float b) {
    unsigned int r;
    asm("v_cvt_pk_bf16_f32 %0, %1, %2" : "=v"(r) : "v"(a), "v"(b));
    return r;
}
// Volatile global loads: cannot be sunk/spilled by MachineSink — stay issued
// at step top, in flight under the MFMA phase. Manual vmcnt at use point.
__device__ __forceinline__ float4v gload4f(const float* p) {
    float4v r;
    asm volatile("global_load_dwordx4 %0, %1, off" : "=v"(r) : "v"(p));
    return r;
}
__device__ __forceinline__ uint4v gload4u(const unsigned short* p) {
    uint4v r;
    asm volatile("global_load_dwordx4 %0, %1, off" : "=v"(r) : "v"(p));
    return r;
}
#define VM_WAIT0  do { asm volatile("s_waitcnt vmcnt(0)" ::: "memory"); \
                       __builtin_amdgcn_sched_barrier(0); } while (0)

// ---- fused routing: count -> plan -> scatter in ONE block ----
__global__ __launch_bounds__(1024) void route_kernel(const int* __restrict__ sel,
                                                     int* __restrict__ meta) {
    __shared__ int cnt[E_DIM];
    __shared__ int wptr[E_DIM];
    int tid = threadIdx.x;
    if (tid < E_DIM) cnt[tid] = 0;
    __syncthreads();
    int p0 = tid, p1 = tid + 1024;
    int e0 = sel[p0], e1 = sel[p1];
    atomicAdd(&cnt[e0], 1);
    atomicAdd(&cnt[e1], 1);
    for (int i = tid; i < MAXCH * PM; i += 1024) meta[LIST_OFF + i] = -1;
    __syncthreads();
    if (tid == 0) {
        int off = 0, ci = 0;
        for (int e = 0; e < E_DIM; ++e) {
            wptr[e] = off;
            int nch = (cnt[e] + PM - 1) / PM;
            for (int j = 0; j < nch; ++j) meta[32 + ci++] = e;
            off += nch * PM;
        }
        for (; ci < MAXCH; ++ci) meta[32 + ci] = -1;
    }
    __syncthreads();
    int pos0 = atomicAdd(&wptr[e0], 1);
    meta[LIST_OFF + pos0] = p0;
    int pos1 = atomicAdd(&wptr[e1], 1);
    meta[LIST_OFF + pos1] = p1;
}

// ---- GEMM 1 (MFMA bf16): h = silu(x.w0d^T) * (x.w1d^T), 256(pairs) x 64(i) tile ----
// 1024 threads = 16 waves; wave-tile 16(pairs) x 64(i). Weights read exactly once.
// Pipelined: asm-volatile loads issue at step top (in flight under MFMA);
// vmcnt(0) + cvt + ds_write buf[cur^1]; ONE barrier per step.
__global__ __launch_bounds__(1024, 4) void gemm01_kernel(
    const float* __restrict__ x, const float* __restrict__ w0g,
    const float* __restrict__ w1g, const float* __restrict__ s0,
    const float* __restrict__ s1, const int* __restrict__ meta,
    unsigned short* __restrict__ hbuf) {
    int e = meta[32 + blockIdx.y];
    if (e < 0) return;
    int itile = blockIdx.x;                 // 0..15 (I/64)
    int tid = threadIdx.x;

    __shared__ unsigned short xs[2][PM][LDB];   // 72 KB
    __shared__ unsigned short as_[2][64][LDB];  // 18 KB
    __shared__ unsigned short bs_[2][64][LDB];  // 18 KB
    __shared__ int prow[PM];
    __shared__ int trow[PM];

    if (tid < PM) {
        int p = meta[LIST_OFF + blockIdx.y * PM + tid];
        prow[tid] = p;
        trow[tid] = p >= 0 ? (p >> 2) : 0;  // token = pair/4
    }
    __syncthreads();

    const int lane = tid & 63;
    const int wid  = tid >> 6;              // 0..15 -> 16-row m-strip
    const int l15  = lane & 15;
    const int kq   = (lane >> 4) * 8;       // fragment k sub-offset
    const int ib   = itile >> 1;            // i-block (128) for scales

    float4v zero = {0.f, 0.f, 0.f, 0.f};
    float4v accg[4], accu[4];
#pragma unroll
    for (int t = 0; t < 4; ++t) { accg[t] = zero; accu[t] = zero; }

    // staging maps: x = 4 thr/row x 16 f32; weights = 16 thr/row x 4 f32
    const int rx = tid >> 2, cx = tid & 3;
    const int rww = tid >> 4, cw = tid & 15;
    const float* xrow  = x   + (size_t)trow[rx] * H_DIM + cx * 16;
    const float* w0row = w0g + ((size_t)e * I_DIM + itile * 64 + rww) * H_DIM + cw * 4;
    const float* w1row = w1g + ((size_t)e * I_DIM + itile * 64 + rww) * H_DIM + cw * 4;
    const float* s0p = s0 + ((size_t)e * (I_DIM/128) + ib) * (H_DIM/128);
    const float* s1p = s1 + ((size_t)e * (I_DIM/128) + ib) * (H_DIM/128);

    float4v px[4], pa, pb;
    {   // prologue: plain loads (compiler-managed waits), write step 0 into buf 0
#pragma unroll
        for (int q = 0; q < 4; ++q) px[q] = *(const float4v*)(xrow + q * 4);
        pa = *(const float4v*)(w0row);
        pb = *(const float4v*)(w1row);
        float sg = s0p[0], su = s1p[0];
#pragma unroll
        for (int j = 0; j < 2; ++j) {
            uint4v v = {cvt2(px[2*j][0], px[2*j][1]),   cvt2(px[2*j][2], px[2*j][3]),
                        cvt2(px[2*j+1][0], px[2*j+1][1]), cvt2(px[2*j+1][2], px[2*j+1][3])};
            *(uint4v*)&xs[0][rx][cx * 16 + j * 8] = v;
        }
        *(uint2*)&as_[0][rww][cw * 4] = make_uint2(cvt2(pa[0] * sg, pa[1] * sg),
                                                   cvt2(pa[2] * sg, pa[3] * sg));
        *(uint2*)&bs_[0][rww][cw * 4] = make_uint2(cvt2(pb[0] * su, pb[1] * su),
                                                   cvt2(pb[2] * su, pb[3] * su));
    }
    __syncthreads();

    const int NT = H_DIM / BK2;             // 32 steps
    int cur = 0;
    for (int t = 0; t < NT; ++t) {
        if (t + 1 < NT) {                   // issue next-step loads (volatile: pinned here)
            const int h0 = (t + 1) * BK2;
            px[0] = gload4f(xrow + h0);
            px[1] = gload4f(xrow + h0 + 4);
            px[2] = gload4f(xrow + h0 + 8);
            px[3] = gload4f(xrow + h0 + 12);
            pa = gload4f(w0row + h0);
            pb = gload4f(w1row + h0);
        }
        __builtin_amdgcn_sched_barrier(0);
#pragma unroll
        for (int ks = 0; ks < BK2 / 32; ++ks) {
            int koff = ks * 32 + kq;
            short8v af = *(const short8v*)&xs[cur][wid * 16 + l15][koff];
#pragma unroll
            for (int nt = 0; nt < 4; ++nt) {
                short8v b0 = *(const short8v*)&as_[cur][nt * 16 + l15][koff];
                accg[nt] = __builtin_amdgcn_mfma_f32_16x16x32_bf16(af, b0, accg[nt], 0, 0, 0);
                short8v b1 = *(const short8v*)&bs_[cur][nt * 16 + l15][koff];
                accu[nt] = __builtin_amdgcn_mfma_f32_16x16x32_bf16(af, b1, accu[nt], 0, 0, 0);
            }
        }
        __builtin_amdgcn_sched_barrier(0);
        if (t + 1 < NT) {                   // drain loads, cvt + write buf[cur^1]
            VM_WAIT0;
            float sg = s0p[(t + 1) >> 1], su = s1p[(t + 1) >> 1];
#pragma unroll
            for (int j = 0; j < 2; ++j) {
                uint4v v = {cvt2(px[2*j][0], px[2*j][1]),   cvt2(px[2*j][2], px[2*j][3]),
                            cvt2(px[2*j+1][0], px[2*j+1][1]), cvt2(px[2*j+1][2], px[2*j+1][3])};
                *(uint4v*)&xs[cur ^ 1][rx][cx * 16 + j * 8] = v;
            }
            *(uint2*)&as_[cur ^ 1][rww][cw * 4] = make_uint2(cvt2(pa[0] * sg, pa[1] * sg),
                                                             cvt2(pa[2] * sg, pa[3] * sg));
            *(uint2*)&bs_[cur ^ 1][rww][cw * 4] = make_uint2(cvt2(pb[0] * su, pb[1] * su),
                                                             cvt2(pb[2] * su, pb[3] * su));
        }
        __syncthreads();
        cur ^= 1;
    }

    // epilogue: C layout col=lane&15 (i), row=(lane>>4)*4+reg (pair)
    int rowb = wid * 16 + (lane >> 4) * 4;
    int colb = itile * 64 + l15;
#pragma unroll
    for (int nt = 0; nt < 4; ++nt) {
#pragma unroll
        for (int rg = 0; rg < 4; ++rg) {
            int p = prow[rowb + rg];
            if (p < 0) continue;
            float g = accg[nt][rg], u = accu[nt][rg];
            float h = g / (1.f + __expf(-g)) * u;
            hbuf[(size_t)p * I_DIM + colb + nt * 16] = (unsigned short)bfr(h);
        }
    }
}

// ---- GEMM 2 (MFMA bf16): out[p,:] = (h.w2d^T) * rw[p], 256(pairs) x 64(h) tile ----
// Same pipelined structure. 1024 threads = 16 waves. grid: x = htile (32), y = chunk.
__global__ __launch_bounds__(1024, 4) void gemm2_kernel(
    const unsigned short* __restrict__ hbuf, const float* __restrict__ w2g,
    const float* __restrict__ s2, const float* __restrict__ rw,
    const int* __restrict__ meta, float* __restrict__ out) {
    int e = meta[32 + blockIdx.y];
    if (e < 0) return;
    int htile = blockIdx.x;                 // 0..31 (H/64)
    int tid = threadIdx.x;

    __shared__ unsigned short hs[2][PM][LDB];   // 72 KB
    __shared__ unsigned short wsm[2][64][LDB];  // 18 KB
    __shared__ int prow[PM];

    if (tid < PM) prow[tid] = meta[LIST_OFF + blockIdx.y * PM + tid];
    __syncthreads();

    const int lane = tid & 63;
    const int wid  = tid >> 6;              // 0..15
    const int l15  = lane & 15;
    const int kq   = (lane >> 4) * 8;
    const int hbk  = htile >> 1;            // h-block (128) for scales

    float4v zero = {0.f, 0.f, 0.f, 0.f};
    float4v acc[4];
#pragma unroll
    for (int t = 0; t < 4; ++t) acc[t] = zero;

    const int rx = tid >> 2, cx = tid & 3;   // h: 4 thr/row x 16 bf16
    const int rww = tid >> 4, cw = tid & 15; // w2: 16 thr/row x 4 f32
    int pr = prow[rx]; if (pr < 0) pr = 0;
    const unsigned short* hrow = hbuf + (size_t)pr * I_DIM + cx * 16;
    const float* wrow = w2g + ((size_t)e * H_DIM + htile * 64 + rww) * I_DIM + cw * 4;
    const float* s2p = s2 + ((size_t)e * (H_DIM/128) + hbk) * (I_DIM/128);

    uint4v ph[2];
    float4v pw;
    {   // prologue
        ph[0] = *(const uint4v*)(hrow);
        ph[1] = *(const uint4v*)(hrow + 8);
        pw = *(const float4v*)(wrow);
        float sc = s2p[0];
        *(uint4v*)&hs[0][rx][cx * 16]     = ph[0];
        *(uint4v*)&hs[0][rx][cx * 16 + 8] = ph[1];
        *(uint2*)&wsm[0][rww][cw * 4] = make_uint2(cvt2(pw[0] * sc, pw[1] * sc),
                                                   cvt2(pw[2] * sc, pw[3] * sc));
    }
    __syncthreads();

    const int NT2 = I_DIM / BK2;            // 16 steps
    int cur = 0;
    for (int t = 0; t < NT2; ++t) {
        if (t + 1 < NT2) {                  // issue next-step loads (volatile: pinned here)
            const int i0 = (t + 1) * BK2;
            ph[0] = gload4u(hrow + i0);
            ph[1] = gload4u(hrow + i0 + 8);
            pw = gload4f(wrow + i0);
        }
        __builtin_amdgcn_sched_barrier(0);
#pragma unroll
        for (int ks = 0; ks < BK2 / 32; ++ks) {
            int koff = ks * 32 + kq;
            short8v af = *(const short8v*)&hs[cur][wid * 16 + l15][koff];
#pragma unroll
            for (int nt = 0; nt < 4; ++nt) {
                short8v bfv = *(const short8v*)&wsm[cur][nt * 16 + l15][koff];
                acc[nt] = __builtin_amdgcn_mfma_f32_16x16x32_bf16(af, bfv, acc[nt], 0, 0, 0);
            }
        }
        __builtin_amdgcn_sched_barrier(0);
        if (t + 1 < NT2) {                  // drain loads, write buf[cur^1]
            VM_WAIT0;
            float sc = s2p[(t + 1) >> 1];
            *(uint4v*)&hs[cur ^ 1][rx][cx * 16]     = ph[0];
            *(uint4v*)&hs[cur ^ 1][rx][cx * 16 + 8] = ph[1];
            *(uint2*)&wsm[cur ^ 1][rww][cw * 4] = make_uint2(cvt2(pw[0] * sc, pw[1] * sc),
                                                             cvt2(pw[2] * sc, pw[3] * sc));
        }
        __syncthreads();
        cur ^= 1;
    }

    int rowb = wid * 16 + (lane >> 4) * 4;
    int colb = htile * 64 + l15;
#pragma unroll
    for (int nt = 0; nt < 4; ++nt) {
#pragma unroll
        for (int rg = 0; rg < 4; ++rg) {
            int p = prow[rowb + rg];
            if (p < 0) continue;
            out[(size_t)p * H_DIM + colb + nt * 16] = acc[nt][rg] * rw[p];
        }
    }
}

extern "C" void kernel_launch(void* const* d_in, const int* in_sizes, int n_in,
                              void* d_out, int out_size, void* d_ws, size_t ws_size,
                              hipStream_t stream) {
    const float* x  = (const float*)d_in[0];
    const float* w0 = (const float*)d_in[1];
    const float* w1 = (const float*)d_in[2];
    const float* w2 = (const float*)d_in[3];
    const float* s0 = (const float*)d_in[4];
    const float* s1 = (const float*)d_in[5];
    const float* s2 = (const float*)d_in[6];
    const int* sel  = (const int*)d_in[7];
    const float* rw = (const float*)d_in[8];
    float* out = (float*)d_out;
    int* meta = (int*)d_ws;
    unsigned short* hbuf = (unsigned short*)((float*)d_ws + HWS_OFF);  // 2048*1024 bf16 = 4 MB

    route_kernel<<<1, 1024, 0, stream>>>(sel, meta);
    gemm01_kernel<<<dim3(I_DIM / 64, MAXCH), 1024, 0, stream>>>(x, w0, w1, s0, s1, meta, hbuf);
    gemm2_kernel<<<dim3(H_DIM / 64, MAXCH), 1024, 0, stream>>>(hbuf, w2, s2, rw, meta, out);
}